// Round 5
// baseline (506.961 us; speedup 1.0000x reference)
//
#include <hip/hip_runtime.h>
#include <hip/hip_bf16.h>
#include <cstdint>
#include <cstddef>

// ---------------------------------------------------------------------------
// SelfAttention: qkv = x@Wqkv^T ; P' = exp(Q@K^T*0.125) ; l = rowsum(P') ;
// O' = P'@V ; y = (O'@Wout^T)/l + b.  bf16 MFMA GEMMs (fp32 accum).
// R5: inner MFMA switched to 32x32x16 (8.07cyc/32k FLOP vs 4.85/16k = -17%
// MFMA-pipe cycles, half the MFMA inst count); casts fused into one kernel.
// Keeps R4's BK=64 XOR-swizzled LDS (0 bank conflicts) + fused exp/rowsum.
// ---------------------------------------------------------------------------

typedef __bf16 bf16x8 __attribute__((ext_vector_type(8)));
typedef float f32x16 __attribute__((ext_vector_type(16)));

__device__ __forceinline__ void gl_lds16(const void* g, void* l) {
  __builtin_amdgcn_global_load_lds((const __attribute__((address_space(1))) void*)g,
                                   (__attribute__((address_space(3))) void*)l, 16, 0, 0);
}

// ---------------- fused cast fp32 -> bf16 for x, w_qkv, w_out ----------------
// x: 16777216 elems = 8192 blocks; w_qkv: 3145728 = 1536; w_out: 1048576 = 512.
__global__ __launch_bounds__(256) void cast3_f32_bf16(
    const float* __restrict__ x, __hip_bfloat16* __restrict__ Xb,
    const float* __restrict__ wq, __hip_bfloat16* __restrict__ Wq,
    const float* __restrict__ wo, __hip_bfloat16* __restrict__ Wo) {
  const int b = blockIdx.x;
  const float* in; __hip_bfloat16* out; int base;
  if (b < 8192)       { in = x;  out = Xb; base = b * 2048; }
  else if (b < 9728)  { in = wq; out = Wq; base = (b - 8192) * 2048; }
  else                { in = wo; out = Wo; base = (b - 9728) * 2048; }
  const int i = base + threadIdx.x * 8;
  float4 a = *(const float4*)(in + i);
  float4 c = *(const float4*)(in + i + 4);
  __align__(16) __hip_bfloat16 o[8];
  o[0] = __float2bfloat16(a.x); o[1] = __float2bfloat16(a.y);
  o[2] = __float2bfloat16(a.z); o[3] = __float2bfloat16(a.w);
  o[4] = __float2bfloat16(c.x); o[5] = __float2bfloat16(c.y);
  o[6] = __float2bfloat16(c.z); o[7] = __float2bfloat16(c.w);
  *(uint4*)(out + i) = *(const uint4*)o;
}

// ============ shared GEMM core: BK=64, XOR-swizzled LDS, 32x32x16 MFMA ============
// C = A @ B^T ; A:[M,K] bf16 lda, B:[N,K] bf16 ldb, both row-major over K.
// 128x128 tile, BK=64 (4 k-steps of 16), 4 waves 2x2 (64x64/wave = 2x2 MFMAs),
// global_load_lds width=16. LDS row stride 64 elems; 16B chunk at (row, slot s)
// holds global k-chunk s^(row&7) (conflict-free per R4 measurement).
// A/B operand layout: [m=lane&31][k=(lane>>5)*8+j]; at k-step t the needed
// global chunk is 2t+h (h=lane>>5), slot = (2t+h)^(lane&7).
#define GEMM_CORE64(APTR, LDA, BPTR, LDB, KLEN)                                    \
  __shared__ __align__(16) __hip_bfloat16 As[128 * 64];                            \
  __shared__ __align__(16) __hip_bfloat16 Bs[128 * 64];                            \
  const int tid  = threadIdx.x;                                                    \
  const int lane = tid & 63;                                                       \
  const int l31  = lane & 31;                                                      \
  const int h    = lane >> 5;                                                      \
  const int wave = tid >> 6;                                                       \
  const int wr   = wave >> 1;                                                      \
  const int wc   = wave & 1;                                                       \
  const int row0 = blockIdx.y * 128;                                               \
  const int col0 = blockIdx.x * 128;                                               \
  /* staging: 1024 16B-chunks per matrix, 4/thread; chunk c -> LDS byte c*16. */   \
  /* source: row=c>>3, global k-chunk = (c&7)^(row&7).                        */   \
  unsigned offA[4], offB[4];                                                       \
  _Pragma("unroll") for (int i = 0; i < 4; ++i) {                                  \
    const int c = tid + 256 * i;                                                   \
    const int r = c >> 3, kc = ((c ^ (c >> 3)) & 7) * 8;                           \
    offA[i] = (unsigned)(row0 + r) * (unsigned)(LDA) + kc;                         \
    offB[i] = (unsigned)(col0 + r) * (unsigned)(LDB) + kc;                         \
  }                                                                                \
  f32x16 acc[2][2];                                                                \
  _Pragma("unroll") for (int i = 0; i < 2; ++i)                                    \
    _Pragma("unroll") for (int j = 0; j < 2; ++j)                                  \
      _Pragma("unroll") for (int e = 0; e < 16; ++e) acc[i][j][e] = 0.f;           \
  /* per-step slot offsets (elems): ((2t+h)^(l31&7))*8 */                          \
  int soff[4];                                                                     \
  _Pragma("unroll") for (int t = 0; t < 4; ++t)                                    \
    soff[t] = ((2 * t + h) ^ (l31 & 7)) * 8;                                       \
  const int arow0 = wr * 64 + l31;   /* + bi*32 */                                 \
  const int brow0 = wc * 64 + l31;   /* + bj*32 */                                 \
  for (int k0 = 0; k0 < (KLEN); k0 += 64) {                                        \
    _Pragma("unroll") for (int i = 0; i < 4; ++i) {                                \
      gl_lds16((APTR) + offA[i] + k0, As + ((size_t)tid + 256 * i) * 8);           \
      gl_lds16((BPTR) + offB[i] + k0, Bs + ((size_t)tid + 256 * i) * 8);           \
    }                                                                              \
    __syncthreads();                                                               \
    _Pragma("unroll") for (int t = 0; t < 4; ++t) {                                \
      bf16x8 af[2], bfr[2];                                                        \
      _Pragma("unroll") for (int bi = 0; bi < 2; ++bi)                             \
        af[bi] = *(const bf16x8*)(As + (arow0 + bi * 32) * 64 + soff[t]);          \
      _Pragma("unroll") for (int bj = 0; bj < 2; ++bj)                             \
        bfr[bj] = *(const bf16x8*)(Bs + (brow0 + bj * 32) * 64 + soff[t]);         \
      _Pragma("unroll") for (int bi = 0; bi < 2; ++bi)                             \
        _Pragma("unroll") for (int bj = 0; bj < 2; ++bj)                           \
          acc[bi][bj] = __builtin_amdgcn_mfma_f32_32x32x16_bf16(af[bi], bfr[bj],   \
                                                                acc[bi][bj],0,0,0);\
    }                                                                              \
    __syncthreads();                                                               \
  }                                                                                \
  /* C/D layout (m74/m101): col = lane&31, row = (reg&3)+8*(reg>>2)+4*h */         \
  const int crow = row0 + wr * 64 + 4 * h;  /* + bi*32 + rp(reg) */                \
  const int ccol = col0 + wc * 64 + l31;    /* + bj*32 */

#define RP(reg) (((reg) & 3) + 8 * ((reg) >> 2))

// ---------------- batched gemm ----------------
// OUT_MODE: 0 = bf16 out; 2 = f32 out * (1/rsum[row]) + bias[col]
template<int OUT_MODE>
__global__ __launch_bounds__(256) void gemm_bt(
    const __hip_bfloat16* __restrict__ A, int lda, long long sA,
    const __hip_bfloat16* __restrict__ B, int ldb, long long sB,
    void* __restrict__ Cv, int ldc, long long sC,
    const float* __restrict__ bias, const float* __restrict__ rsum, int K)
{
  const int bz = blockIdx.z;
  GEMM_CORE64(A + (size_t)bz * sA, lda, B + (size_t)bz * sB, ldb, K)
  if constexpr (OUT_MODE == 0) {
    __hip_bfloat16* C = (__hip_bfloat16*)Cv + (size_t)bz * sC;
    #pragma unroll
    for (int bi = 0; bi < 2; ++bi)
      #pragma unroll
      for (int bj = 0; bj < 2; ++bj)
        #pragma unroll
        for (int reg = 0; reg < 16; ++reg)
          C[(size_t)(crow + bi * 32 + RP(reg)) * ldc + ccol + bj * 32] =
              __float2bfloat16(acc[bi][bj][reg]);
  } else {
    float* C = (float*)Cv + (size_t)bz * sC;
    float bv[2];
    #pragma unroll
    for (int bj = 0; bj < 2; ++bj) bv[bj] = bias[ccol + bj * 32];
    #pragma unroll
    for (int bi = 0; bi < 2; ++bi)
      #pragma unroll
      for (int reg = 0; reg < 16; ++reg) {
        const int row = crow + bi * 32 + RP(reg);
        const float sc = 1.f / rsum[row];
        #pragma unroll
        for (int bj = 0; bj < 2; ++bj)
          C[(size_t)row * ldc + ccol + bj * 32] = acc[bi][bj][reg] * sc + bv[bj];
      }
  }
}

// ---------------- QK^T gemm, fused exp epilogue + atomic row sums ----------------
// P' = exp(acc*0.125) (bf16); Lsum[row] += rowsum of the bf16-rounded P' tile.
__global__ __launch_bounds__(256) void gemm_qk_exp(
    const __hip_bfloat16* __restrict__ A, int lda, long long sA,
    const __hip_bfloat16* __restrict__ B, int ldb, long long sB,
    __hip_bfloat16* __restrict__ Pv, int ldc, long long sC,
    float* __restrict__ Lsum, int ldl, int K)
{
  const int bz = blockIdx.z;
  GEMM_CORE64(A + (size_t)bz * sA, lda, B + (size_t)bz * sB, ldb, K)
  __hip_bfloat16* C = Pv + (size_t)bz * sC;
  float* Lrow = Lsum + (size_t)bz * ldl;
  #pragma unroll
  for (int bi = 0; bi < 2; ++bi) {
    #pragma unroll
    for (int reg = 0; reg < 16; ++reg) {
      const int row = crow + bi * 32 + RP(reg);
      float s = 0.f;
      #pragma unroll
      for (int bj = 0; bj < 2; ++bj) {
        const float e = __expf(acc[bi][bj][reg] * 0.125f);
        const __hip_bfloat16 hh = __float2bfloat16(e);
        C[(size_t)row * ldc + ccol + bj * 32] = hh;
        s += __bfloat162float(hh);
      }
      // reduce across the 32 lanes of this half-wave (cols), 1 atomic/row/half
      #pragma unroll
      for (int mask = 1; mask < 32; mask <<= 1) s += __shfl_xor(s, mask);
      if (l31 == 0) atomicAdd(&Lrow[row], s);
    }
  }
}

// ---------------- QKV gemm with split epilogue ----------------
// Cols 0..2047 (Q,K) -> QK [M, 2048] bf16. Cols 2048..3071 (V) -> Vt [1024, M]
// (transposed). Branch is block-uniform (blockIdx.x < 16 => Q/K, >= 16 => V).
__global__ __launch_bounds__(256) void gemm_qkv(
    const __hip_bfloat16* __restrict__ A, int lda,
    const __hip_bfloat16* __restrict__ B, int ldb,
    __hip_bfloat16* __restrict__ QK,
    __hip_bfloat16* __restrict__ Vt, int M, int K)
{
  GEMM_CORE64(A, lda, B, ldb, K)
  if (blockIdx.x < 16) {
    #pragma unroll
    for (int bi = 0; bi < 2; ++bi)
      #pragma unroll
      for (int bj = 0; bj < 2; ++bj)
        #pragma unroll
        for (int reg = 0; reg < 16; ++reg)
          QK[(size_t)(crow + bi * 32 + RP(reg)) * 2048 + ccol + bj * 32] =
              __float2bfloat16(acc[bi][bj][reg]);
  } else {
    // V scatter: regs 4c..4c+3 are rows 8c..8c+3 (consecutive) -> one uint2 each
    #pragma unroll
    for (int bi = 0; bi < 2; ++bi) {
      #pragma unroll
      for (int c = 0; c < 4; ++c) {
        const int rowb = crow + bi * 32 + 8 * c;  // multiple of 4 -> 8B-aligned
        #pragma unroll
        for (int bj = 0; bj < 2; ++bj) {
          const int vc = ccol + bj * 32 - 2048;
          __align__(8) __hip_bfloat16 o[4];
          #pragma unroll
          for (int r = 0; r < 4; ++r) o[r] = __float2bfloat16(acc[bi][bj][4 * c + r]);
          *(uint2*)(Vt + (size_t)vc * M + rowb) = *(const uint2*)o;
        }
      }
    }
  }
}

// ---------------------------------------------------------------------------
extern "C" void kernel_launch(void* const* d_in, const int* in_sizes, int n_in,
                              void* d_out, int out_size, void* d_ws, size_t ws_size,
                              hipStream_t stream) {
  const float* x     = (const float*)d_in[0];   // [8, 2048, 1024]
  const float* w_qkv = (const float*)d_in[1];   // [3072, 1024]
  const float* w_out = (const float*)d_in[2];   // [1024, 1024]
  const float* b_out = (const float*)d_in[3];   // [1024]
  float* out = (float*)d_out;

  constexpr int Bz = 8, N = 2048, D = 1024, E = 3 * D;
  constexpr int M = Bz * N;  // 16384

  // ---- workspace: fixed regions + one dynamic region (aliased) ----
  char* p = (char*)d_ws;
  __hip_bfloat16* Wo = (__hip_bfloat16*)p; p += (size_t)D * D * 2;
  __hip_bfloat16* Vt = (__hip_bfloat16*)p; p += (size_t)D * M * 2;
  __hip_bfloat16* QK = (__hip_bfloat16*)p; p += (size_t)M * 2 * D * 2;
  __hip_bfloat16* AO = (__hip_bfloat16*)p; p += (size_t)M * D * 2;
  float*          L  = (float*)p;          p += (size_t)M * 4;
  char* dyn = p;
  const size_t fixed_sz = (size_t)(dyn - (char*)d_ws);
  const size_t xw_sz = (size_t)M * D * 2 + (size_t)E * D * 2;  // Xb + Wq

  int G = 1;
  for (int g = 8; g >= 1; g >>= 1) {
    size_t dyn_sz = (size_t)g * N * N * 2;  // P' bf16
    if (dyn_sz < xw_sz) dyn_sz = xw_sz;
    if (fixed_sz + dyn_sz <= ws_size) { G = g; break; }
  }

  __hip_bfloat16* Xb = (__hip_bfloat16*)dyn;
  __hip_bfloat16* Wq = (__hip_bfloat16*)(dyn + (size_t)M * D * 2);
  __hip_bfloat16* P  = (__hip_bfloat16*)dyn;

  // phase 1: fused casts + zero row-sum accumulator + QKV projection
  hipMemsetAsync(L, 0, (size_t)M * 4, stream);
  cast3_f32_bf16<<<10240, 256, 0, stream>>>(x, Xb, w_qkv, Wq, w_out, Wo);
  gemm_qkv<<<dim3(E / 128, M / 128), 256, 0, stream>>>(Xb, D, Wq, D, QK, Vt, M, D);

  // phases 2-3: batched attention, groups of G
  for (int g = 0; g < Bz / G; ++g) {
    const __hip_bfloat16* Qg = QK + (size_t)g * G * N * (2 * D);
    // P' = exp(Q @ K^T * 0.125) (bf16) + atomic row sums into L
    gemm_qk_exp<<<dim3(N / 128, N / 128, G), 256, 0, stream>>>(
        Qg, 2 * D, (long long)N * 2 * D,
        Qg + D, 2 * D, (long long)N * 2 * D,
        P, N, (long long)N * N,
        L + (size_t)g * G * N, N, D);
    // O' = P' @ Vt^T (bf16, unnormalized)
    gemm_bt<0><<<dim3(D / 128, N / 128, G), 256, 0, stream>>>(
        P, N, (long long)N * N,
        Vt + (size_t)g * G * N, M, (long long)N,
        AO + (size_t)g * G * N * D, D, (long long)N * D,
        nullptr, nullptr, N);
  }

  // phase 4: y = (O' @ Wout^T) / l[row] + b
  gemm_bt<2><<<dim3(D / 128, M / 128, 1), 256, 0, stream>>>(
      AO, D, 0LL, Wo, D, 0LL, out, D, 0LL, b_out, L, D);
}